// Round 5
// baseline (49.637 us; speedup 1.0000x reference)
//
#include <hip/hip_runtime.h>
#include <hip/hip_bf16.h>

// CosSim2D: inputs (32,64,64,64) f32, w (1,576,128) f32, p (128), q (1)
// out (32,64,64,128) f32.
// R5: 2-tile pipelined blocks. Grid 512, each block = 4 output rows (2 tiles),
// ring-5 row-slot LDS. Tile-1 rows issued early (regs) under tile-0 compute;
// tile-0 stores drain under tile-1 compute. B stays fragment-contiguous.

typedef short bf16x8 __attribute__((ext_vector_type(8)));
typedef float f32x4 __attribute__((ext_vector_type(4)));

__device__ __forceinline__ unsigned short f2bf(float f) {
    union { float f; unsigned int u; } v; v.f = f;
    unsigned int u = v.u;
    unsigned int r = (u + 0x7fffu + ((u >> 16) & 1u)) >> 16;  // RNE
    return (unsigned short)r;
}

// ---- pre-kernel: normalize w columns (fp32), store bf16 fragment-contiguous:
// wn2[((tap*2 + kc)*128 + n)*32 + koff] = w_hat[k = tap*64 + kc*32 + koff][n]
__global__ void prep_w_kernel(const float* __restrict__ w,
                              unsigned short* __restrict__ wn2) {
    const int n = blockIdx.x;
    const int lane = threadIdx.x;
    float vals[9];
    float s = 0.f;
#pragma unroll
    for (int i = 0; i < 9; ++i) {
        float v = w[(i * 64 + lane) * 128 + n];
        vals[i] = v;
        s += v * v;
    }
#pragma unroll
    for (int off = 1; off < 64; off <<= 1) s += __shfl_xor(s, off);
    const float inv = 1.0f / sqrtf(fmaxf(s, 1e-12f));
    const int kc = lane >> 5, koff = lane & 31;
#pragma unroll
    for (int i = 0; i < 9; ++i)
        wn2[((i * 2 + kc) * 128 + n) * 32 + koff] = f2bf(vals[i] * inv);
}

#define SLOT 4752   // 66*72
// ---- main: one block = (image b, 4 output rows y0..y0+3); two 2-row tiles
__global__ __launch_bounds__(256, 2) void cossim_main(
    const float* __restrict__ in, const unsigned short* __restrict__ wn,
    const float* __restrict__ p, const float* __restrict__ q,
    float* __restrict__ out) {
    __shared__ unsigned short A[5 * 66 * 72];   // ring of 5 row-slots, 47520 B
    __shared__ float rcsum[256];   // slots 0..3 fp32 row square-sums
    __shared__ float rcj[256];     // junction half-row partials (rows y0+3,y0+4)
    __shared__ float xni[128];
    __shared__ float pfs[128];

    const int tid = (int)threadIdx.x;
    // bijective XCD swizzle: 512 blocks, 8 XCDs, 64 consecutive l per XCD
    const int l = ((int)blockIdx.x & 7) * 64 + ((int)blockIdx.x >> 3);
    const int b = l >> 4, y0 = (l & 15) * 4;
    const float* inb = in + (size_t)b * 262144;

    if (tid < 128) pfs[tid] = expf(p[tid] * 0.2f);

    // ---- stage rows y0-1..y0+2 into slots 0..3 + fused fp32 norm partials
    {
        const int r = tid >> 6;
        const int col = tid & 63;
        const int row = y0 + r - 1;
        unsigned short* dst = &A[r * SLOT + (col + 1) * 72];
        float s = 0.f;
        if ((unsigned)row < 64u) {
            const float4* src = reinterpret_cast<const float4*>(inb + row * 4096 + col * 64);
#pragma unroll
            for (int it = 0; it < 8; ++it) {
                float4 v0 = src[2 * it];
                float4 v1 = src[2 * it + 1];
                s += v0.x * v0.x + v0.y * v0.y + v0.z * v0.z + v0.w * v0.w;
                s += v1.x * v1.x + v1.y * v1.y + v1.z * v1.z + v1.w * v1.w;
                union { float f; unsigned u; } ux, uy, uz, uw;
                uint4 pk;
                ux.f = v0.x; uy.f = v0.y; uz.f = v0.z; uw.f = v0.w;
                pk.x = __builtin_amdgcn_perm(uy.u + 0x8000u, ux.u + 0x8000u, 0x07060302u);
                pk.y = __builtin_amdgcn_perm(uw.u + 0x8000u, uz.u + 0x8000u, 0x07060302u);
                ux.f = v1.x; uy.f = v1.y; uz.f = v1.z; uw.f = v1.w;
                pk.z = __builtin_amdgcn_perm(uy.u + 0x8000u, ux.u + 0x8000u, 0x07060302u);
                pk.w = __builtin_amdgcn_perm(uw.u + 0x8000u, uz.u + 0x8000u, 0x07060302u);
                *reinterpret_cast<uint4*>(dst + it * 8) = pk;
            }
        } else {
            uint4 z; z.x = z.y = z.z = z.w = 0u;
#pragma unroll
            for (int it = 0; it < 8; ++it)
                *reinterpret_cast<uint4*>(dst + it * 8) = z;
        }
        rcsum[tid] = s;
    }
    if (tid < 80) {  // zero border cols 0 and 65 for all 5 slots
        const int r = tid >> 4, side = (tid >> 3) & 1, ch = (tid & 7) * 8;
        uint4 z; z.x = z.y = z.z = z.w = 0u;
        *reinterpret_cast<uint4*>(&A[r * SLOT + side * 65 * 72 + ch]) = z;
    }
    __syncthreads();

    // ---- ISSUE tile-1 rows (y0+3 -> slot 4, y0+4 -> slot 0) into held regs
    const int jhalf = tid >> 7, jt = tid & 127;
    const int jr = jt >> 6, jcol = jt & 63;
    const int jrow = y0 + 3 + jr;
    float4 jv[8];
    if ((unsigned)jrow < 64u) {
        const float4* jsrc = reinterpret_cast<const float4*>(
            inb + jrow * 4096 + jcol * 64 + jhalf * 32);
#pragma unroll
        for (int i = 0; i < 8; ++i) jv[i] = jsrc[i];
    } else {
#pragma unroll
        for (int i = 0; i < 8; ++i) jv[i] = make_float4(0.f, 0.f, 0.f, 0.f);
    }

    // ---- tile-0 xni (rows y0..y0+1) from rcsum slots 0..3
    if (tid < 128) {
        const int ry = tid >> 6, x = tid & 63;
        const float qe = expf(q[0] * (-1.0f / 0.3f));
        float s = 0.f;
#pragma unroll
        for (int dy = 0; dy < 3; ++dy) {
            const float* rs = &rcsum[(ry + dy) * 64];
            if (x > 0) s += rs[x - 1];
            s += rs[x];
            if (x < 63) s += rs[x + 1];
        }
        xni[tid] = 1.0f / (sqrtf(fmaxf(s, 1e-12f)) + qe);
    }

    const int wv = tid >> 6, lane = tid & 63;
    const int lr = lane & 15, lg = lane >> 4;
    const int wm = wv >> 1, wnh = wv & 1;
    const unsigned short* wB = wn + (wnh * 64 + lr) * 32 + lg * 8;

    // ================= TILE 0 =================
    {
        f32x4 acc[4][4] = {};
#pragma unroll
        for (int dy = 0; dy < 3; ++dy) {
#pragma unroll
            for (int dx = 0; dx < 3; ++dx) {
                const int tap = dy * 3 + dx;
#pragma unroll
                for (int kc = 0; kc < 2; ++kc) {
                    const unsigned short* wt = wB + (tap * 2 + kc) * 4096;
                    bf16x8 b0 = *reinterpret_cast<const bf16x8*>(wt);
                    bf16x8 b1 = *reinterpret_cast<const bf16x8*>(wt + 512);
                    bf16x8 b2 = *reinterpret_cast<const bf16x8*>(wt + 1024);
                    bf16x8 b3 = *reinterpret_cast<const bf16x8*>(wt + 1536);
                    const unsigned short* abase =
                        &A[(wm + dy) * SLOT + (lr + dx) * 72 + kc * 32 + lg * 8];
#pragma unroll
                    for (int mf = 0; mf < 4; ++mf) {
                        bf16x8 av = *reinterpret_cast<const bf16x8*>(abase + mf * 16 * 72);
                        acc[mf][0] = __builtin_amdgcn_mfma_f32_16x16x32_bf16(av, b0, acc[mf][0], 0, 0, 0);
                        acc[mf][1] = __builtin_amdgcn_mfma_f32_16x16x32_bf16(av, b1, acc[mf][1], 0, 0, 0);
                        acc[mf][2] = __builtin_amdgcn_mfma_f32_16x16x32_bf16(av, b2, acc[mf][2], 0, 0, 0);
                        acc[mf][3] = __builtin_amdgcn_mfma_f32_16x16x32_bf16(av, b3, acc[mf][3], 0, 0, 0);
                    }
                }
            }
        }
        __syncthreads();   // xni ready; all tile-0 A-reads done
        float* orow = out + ((size_t)(b * 64 + y0 + wm) * 64) * 128;
#pragma unroll
        for (int mf = 0; mf < 4; ++mf) {
#pragma unroll
            for (int i = 0; i < 4; ++i) {
                const int pix = mf * 16 + lg * 4 + i;
                const float xn = xni[wm * 64 + pix];
#pragma unroll
                for (int nf = 0; nf < 4; ++nf) {
                    const int n = wnh * 64 + nf * 16 + lr;
                    float sim = acc[mf][nf][i] * xn;
                    float aa = fabsf(sim) + 1e-6f;
                    float r = exp2f(pfs[n] * log2f(aa));
                    orow[(size_t)pix * 128 + n] = copysignf(r, sim);
                }
            }
        }
    }

    // ---- junction: consume held regs -> norms + pack + ds_write slots 4,0
    {
        float s = 0.f;
#pragma unroll
        for (int i = 0; i < 8; ++i)
            s += jv[i].x * jv[i].x + jv[i].y * jv[i].y + jv[i].z * jv[i].z + jv[i].w * jv[i].w;
        rcj[tid] = s;
        const int slot = jr ? 0 : 4;
        unsigned short* dst = &A[slot * SLOT + (jcol + 1) * 72 + jhalf * 32];
#pragma unroll
        for (int i = 0; i < 4; ++i) {
            union { float f; unsigned u; } ux, uy, uz, uw;
            uint4 pk;
            float4 v0 = jv[2 * i], v1 = jv[2 * i + 1];
            ux.f = v0.x; uy.f = v0.y; uz.f = v0.z; uw.f = v0.w;
            pk.x = __builtin_amdgcn_perm(uy.u + 0x8000u, ux.u + 0x8000u, 0x07060302u);
            pk.y = __builtin_amdgcn_perm(uw.u + 0x8000u, uz.u + 0x8000u, 0x07060302u);
            ux.f = v1.x; uy.f = v1.y; uz.f = v1.z; uw.f = v1.w;
            pk.z = __builtin_amdgcn_perm(uy.u + 0x8000u, ux.u + 0x8000u, 0x07060302u);
            pk.w = __builtin_amdgcn_perm(uw.u + 0x8000u, uz.u + 0x8000u, 0x07060302u);
            *reinterpret_cast<uint4*>(dst + i * 8) = pk;
        }
    }
    __syncthreads();

    // ---- tile-1 xni (rows y0+2..y0+3): slots 2,3 from rcsum; rows y0+3/4 from rcj
    if (tid < 128) {
        const int ry = tid >> 6, x = tid & 63;
        const float qe = expf(q[0] * (-1.0f / 0.3f));
        float s = 0.f;
#pragma unroll
        for (int dy = 0; dy < 3; ++dy) {
            const int idx = ry + dy;   // 0..3 -> input row y0+1+idx
#pragma unroll
            for (int dc = -1; dc <= 1; ++dc) {
                const int c = x + dc;
                if ((unsigned)c < 64u) {
                    float rs;
                    if (idx < 2) rs = rcsum[(idx + 2) * 64 + c];
                    else rs = rcj[(idx - 2) * 64 + c] + rcj[128 + (idx - 2) * 64 + c];
                    s += rs;
                }
            }
        }
        xni[tid] = 1.0f / (sqrtf(fmaxf(s, 1e-12f)) + qe);
    }

    // ================= TILE 1 =================
    {
        f32x4 acc[4][4] = {};
#pragma unroll
        for (int dy = 0; dy < 3; ++dy) {
#pragma unroll
            for (int dx = 0; dx < 3; ++dx) {
                const int tap = dy * 3 + dx;
#pragma unroll
                for (int kc = 0; kc < 2; ++kc) {
                    const unsigned short* wt = wB + (tap * 2 + kc) * 4096;
                    bf16x8 b0 = *reinterpret_cast<const bf16x8*>(wt);
                    bf16x8 b1 = *reinterpret_cast<const bf16x8*>(wt + 512);
                    bf16x8 b2 = *reinterpret_cast<const bf16x8*>(wt + 1024);
                    bf16x8 b3 = *reinterpret_cast<const bf16x8*>(wt + 1536);
                    int srow = wm + dy + 2;
                    srow = (srow >= 5) ? (srow - 5) : srow;
                    const unsigned short* abase =
                        &A[srow * SLOT + (lr + dx) * 72 + kc * 32 + lg * 8];
#pragma unroll
                    for (int mf = 0; mf < 4; ++mf) {
                        bf16x8 av = *reinterpret_cast<const bf16x8*>(abase + mf * 16 * 72);
                        acc[mf][0] = __builtin_amdgcn_mfma_f32_16x16x32_bf16(av, b0, acc[mf][0], 0, 0, 0);
                        acc[mf][1] = __builtin_amdgcn_mfma_f32_16x16x32_bf16(av, b1, acc[mf][1], 0, 0, 0);
                        acc[mf][2] = __builtin_amdgcn_mfma_f32_16x16x32_bf16(av, b2, acc[mf][2], 0, 0, 0);
                        acc[mf][3] = __builtin_amdgcn_mfma_f32_16x16x32_bf16(av, b3, acc[mf][3], 0, 0, 0);
                    }
                }
            }
        }
        __syncthreads();   // tile-1 xni ready
        float* orow = out + ((size_t)(b * 64 + y0 + 2 + wm) * 64) * 128;
#pragma unroll
        for (int mf = 0; mf < 4; ++mf) {
#pragma unroll
            for (int i = 0; i < 4; ++i) {
                const int pix = mf * 16 + lg * 4 + i;
                const float xn = xni[wm * 64 + pix];
#pragma unroll
                for (int nf = 0; nf < 4; ++nf) {
                    const int n = wnh * 64 + nf * 16 + lr;
                    float sim = acc[mf][nf][i] * xn;
                    float aa = fabsf(sim) + 1e-6f;
                    float r = exp2f(pfs[n] * log2f(aa));
                    orow[(size_t)pix * 128 + n] = copysignf(r, sim);
                }
            }
        }
    }
}

extern "C" void kernel_launch(void* const* d_in, const int* in_sizes, int n_in,
                              void* d_out, int out_size, void* d_ws, size_t ws_size,
                              hipStream_t stream) {
    (void)in_sizes; (void)n_in; (void)out_size; (void)ws_size;
    const float* in = (const float*)d_in[0];
    const float* w  = (const float*)d_in[1];
    const float* p  = (const float*)d_in[2];
    const float* q  = (const float*)d_in[3];
    float* out = (float*)d_out;
    unsigned short* wn = (unsigned short*)d_ws;  // 18*128*32 bf16 = 147456 B

    prep_w_kernel<<<128, 64, 0, stream>>>(w, wn);
    cossim_main<<<512, 256, 0, stream>>>(in, wn, p, q, out);
}